// Round 7
// baseline (325.181 us; speedup 1.0000x reference)
//
#include <hip/hip_runtime.h>

// SESConv via implicit GEMM on bf16 MFMA (gfx950).
// out[b,o,g,h,w] = sum_{rbase valid, ic, xk, yk} Kc[g,rbase,pos,ic,o] * X[b,ic,src(g,rbase), h+xk-2, w+yk-2]
// Kc[...] = sum_f weight[o,ic,rbase,f] * basis[f,g,xk,yk]
// x: (8,16,12,128,128) f32; weight: (16,16,4,9) f32; basis: (9,12,5,5) f32; out: (8,16,12,128,128) f32
//
// R7: LDS B-read traffic is invariant per (wave,slice) — the only lever is users per
// staged slice. Block now owns TWO r0-columns (6 g's, acc[6][4] = 96 regs, tile 16x16,
// wave = 4 rows). Slice (r_in,s_in) feeds up to 4 (g,rbase) users sharing each bfv
// ds_read: avg users 1.67 -> 2.22, LDS reads x0.75, stagings 12->9 per column-pair.
// Keeps R6's zero-conflict read-layout family (320B rows) and DMA staging (R6 measured
// SQ_LDS_BANK_CONFLICT == 0, WRITE == 98304 clean).

#define NRS 12
#define CIN 16
#define COUT 16
#define HW 128
#define IMG (HW*HW)
#define ICSTRIDE (NRS*IMG)        // x stride between input channels (floats)

// fast-path geometry: tile 16x16, halo 20x20; LDS slice = [half(2)][rl(20)][cl(20)] 16B chunks
#define HALO 20
#define ROWB 320                  // bytes per halo row per half (20 px * 16 B)
#define HALFB 6400                // 400 chunks * 16 B per ic-half
#define NCHUNK 800                // 20*20*2 16B-chunks per slice
#define BUFB 16384                // 1024 chunk slots * 16 B (4 waves * 4 * 64); 224 pad
#define PADW 132
#define PADROWB (PADW*32)         // 4224 B per padded row (132 px * 32 B)

typedef __bf16 bf16x8 __attribute__((ext_vector_type(8)));
typedef float  f32x4  __attribute__((ext_vector_type(4)));

__device__ __forceinline__ unsigned short f2bf(float f) {
    unsigned u = __builtin_bit_cast(unsigned, f);
    u += 0x7fffu + ((u >> 16) & 1u);          // round-nearest-even
    return (unsigned short)(u >> 16);
}

// A-panel: [g(12)][rbase(4)][pp(13)][o(16)][k(32)] bf16, k = possel*16 + ic, pos = 2*pp+possel
// pos==25 -> 0 (pad). 319488 elems = 639 KB.
__global__ void build_kc(const float* __restrict__ wgt, const float* __restrict__ basis,
                         unsigned short* __restrict__ kc) {
    int idx = blockIdx.x * 256 + threadIdx.x;
    const int total = 12 * 4 * 13 * 16 * 32;   // 319488
    if (idx >= total) return;
    int k  = idx & 31;
    int possel = k >> 4, ic = k & 15;
    int o  = (idx >> 5) & 15;
    int t2 = idx >> 9;
    int pp = t2 % 13;
    int gr = t2 / 13;
    int rbase = gr & 3, g = gr >> 2;
    int pos = 2 * pp + possel;
    float s = 0.f;
    if (pos < 25) {
        int xk = pos / 5, yk = pos - 5 * xk;
        #pragma unroll
        for (int f = 0; f < 9; ++f)
            s = fmaf(wgt[((o * CIN + ic) * 4 + rbase) * 9 + f],
                     basis[((f * NRS + g) * 5 + xk) * 5 + yk], s);
    }
    kc[idx] = f2bf(s);
}

// Pre-pass: x (b,ic,s,h,w) f32 -> xbf[b][s][hp 132][wp 132][ic 16] bf16, 2-px zero border.
__global__ void cvt_pad(const float* __restrict__ x, unsigned short* __restrict__ xbf) {
    int idx = blockIdx.x * 256 + threadIdx.x;
    const int total = 8 * 12 * PADW * PADW;    // 1,672,704
    if (idx >= total) return;
    int wp = idx % PADW;
    int t1 = idx / PADW;
    int hp = t1 % PADW;
    int bs = t1 / PADW;                        // b*12 + s
    int s  = bs % 12, bb = bs / 12;
    int h = hp - 2, w = wp - 2;
    bool ok = ((unsigned)h < 128u) && ((unsigned)w < 128u);
    const float* px = x + ((size_t)bb * 192 + s) * IMG + h * HW + w;   // +ic*12*IMG
    unsigned short v[16];
    #pragma unroll
    for (int ic = 0; ic < 16; ++ic) {
        float f = 0.f;
        if (ok) f = px[(size_t)ic * ICSTRIDE];
        v[ic] = f2bf(f);
    }
    uint4 lo, hi;
    lo.x = v[0] | (v[1] << 16);  lo.y = v[2] | (v[3] << 16);
    lo.z = v[4] | (v[5] << 16);  lo.w = v[6] | (v[7] << 16);
    hi.x = v[8] | (v[9] << 16);  hi.y = v[10] | (v[11] << 16);
    hi.z = v[12] | (v[13] << 16); hi.w = v[14] | (v[15] << 16);
    *(uint4*)(xbf + (size_t)idx * 16)     = lo;
    *(uint4*)(xbf + (size_t)idx * 16 + 8) = hi;
}

__global__ __launch_bounds__(256, 2)
void conv_fast(const unsigned short* __restrict__ xbf, const unsigned short* __restrict__ kc,
               float* __restrict__ out) {
    const int b   = blockIdx.z;
    const int R   = blockIdx.y * 2;                // r0-pair {R, R+1}, R in {0,2}
    const int th0 = (blockIdx.x >> 3) * 16;        // 8 row-tiles of 16
    const int tw0 = (blockIdx.x & 7) * 16;         // 8 col-tiles of 16

    const int t    = threadIdx.x;
    const int lane = t & 63;
    const int wave = t >> 6;                       // 0..3, owns 4 output rows
    const int n    = lane & 15;        // MFMA N index
    const int q    = lane >> 4;
    const int possel = q >> 1;
    const int half_  = q & 1;

    __shared__ uint4 xs4[(2 * BUFB) / 16];         // 32768 B, double-buffered
    char* xsc = (char*)xs4;

    // B-fragment byte offsets per K-step (zero-conflict family: 320B rows, 16B/lane)
    int boff[13];
    #pragma unroll
    for (int pp = 0; pp < 13; ++pp) {
        int pos = 2 * pp + possel; if (pos > 24) pos = 24;   // pad tap reads tap 24; A=0 there
        int dx = pos / 5, dy = pos - 5 * dx;
        boff[pp] = half_ * HALFB + dx * ROWB + (n + dy) * 16;
    }
    const int aoff = n * 32 + q * 8;               // A-frag: o*32 + q*8 (ushort elems)

    f32x4 acc[6][4];                               // [c*3+s0][pg], 96 regs
    #pragma unroll
    for (int st = 0; st < 6; ++st)
        #pragma unroll
        for (int pg = 0; pg < 4; ++pg) acc[st][pg] = (f32x4){0.f, 0.f, 0.f, 0.f};

    const char* xb0 = (const char*)xbf;
    const size_t tileoff = ((size_t)th0 * PADW + tw0) * 32;

    // prologue: stage slice (ri=0, si=0): sin = R*3
    {
        const char* sb = xb0 + ((size_t)(b * 12 + R * 3) * PADW * PADW) * 32 + tileoff;
        char* lb = xsc + wave * 4096;
        #pragma unroll
        for (int j = 0; j < 4; ++j) {
            int c = wave * 256 + j * 64 + lane;
            int soff = 0;
            if (c < NCHUNK) {
                int hf = c / 400, p = c - hf * 400;
                int rl = p / 20, cl = p - rl * 20;
                soff = rl * PADROWB + cl * 32 + hf * 16;
            }
            __builtin_amdgcn_global_load_lds(
                (const __attribute__((address_space(1))) void*)(sb + soff),
                (__attribute__((address_space(3))) void*)(lb + j * 1024), 16, 0, 0);
        }
    }
    __syncthreads();
    int cur = 0;

    #pragma unroll 1
    for (int ri = 0; ri < 3; ++ri) {               // r_in = R + ri (mod 4); rolled
        int rr = R + ri; if (rr >= 4) rr -= 4;
        int rrn = rr + 1; if (rrn >= 4) rrn -= 4;
        const bool a0 = (ri <= 1);                 // column c=0 consumes (i = ri)
        const bool a1 = (ri >= 1);                 // column c=1 consumes (i = ri-1)
        #pragma unroll
        for (int si = 0; si < 3; ++si) {           // s_in = si; unrolled: static acc sets
            // ---- issue async stage of next slice into buf[cur^1] ----
            if (!(ri == 2 && si == 2)) {
                int sin_next = (si < 2) ? (rr * 3 + si + 1) : (rrn * 3);
                const char* sb = xb0 + ((size_t)(b * 12 + sin_next) * PADW * PADW) * 32 + tileoff;
                char* lb = xsc + (cur ^ 1) * BUFB + wave * 4096;
                #pragma unroll
                for (int j = 0; j < 4; ++j) {
                    int c = wave * 256 + j * 64 + lane;
                    int soff = 0;
                    if (c < NCHUNK) {
                        int hf = c / 400, p = c - hf * 400;
                        int rl = p / 20, cl = p - rl * 20;
                        soff = rl * PADROWB + cl * 32 + hf * 16;
                    }
                    __builtin_amdgcn_global_load_lds(
                        (const __attribute__((address_space(1))) void*)(sb + soff),
                        (__attribute__((address_space(3))) void*)(lb + j * 1024), 16, 0, 0);
                }
            }

            // ---- GEMM over this slice: up to 4 users share each bfv ds_read ----
            // c0 j0 (ri<=1): rbase=2ri   -> acc[si]
            // c0 j1 (ri<=1, si>0): rbase=2ri+1 -> acc[si-1]
            // c1 j0 (ri>=1): rbase=2(ri-1)   -> acc[3+si]
            // c1 j1 (ri>=1, si>0): rbase=2(ri-1)+1 -> acc[2+si]
            const unsigned short* kA = kc + (size_t)((R * 3 + si) * 4 + 2 * ri) * 6656;
            const unsigned short* kB = kc + (size_t)((R * 3 + si - 1) * 4 + 2 * ri + 1) * 6656;
            const unsigned short* kC = kc + (size_t)(((R + 1) * 3 + si) * 4 + 2 * (ri - 1)) * 6656;
            const unsigned short* kD = kc + (size_t)(((R + 1) * 3 + si - 1) * 4 + 2 * (ri - 1) + 1) * 6656;
            const char* wb = xsc + cur * BUFB + wave * (4 * ROWB);
            #pragma unroll
            for (int pp = 0; pp < 13; ++pp) {
                bf16x8 afA, afB, afC, afD;
                if (a0) {
                    afA = *(const bf16x8*)(kA + pp * 512 + aoff);
                    if (si > 0) afB = *(const bf16x8*)(kB + pp * 512 + aoff);
                }
                if (a1) {
                    afC = *(const bf16x8*)(kC + pp * 512 + aoff);
                    if (si > 0) afD = *(const bf16x8*)(kD + pp * 512 + aoff);
                }
                const char* wp = wb + boff[pp];
                #pragma unroll
                for (int pg = 0; pg < 4; ++pg) {
                    bf16x8 bfv = *(const bf16x8*)(wp + pg * ROWB);
                    if (a0) {
                        acc[si][pg] = __builtin_amdgcn_mfma_f32_16x16x32_bf16(afA, bfv, acc[si][pg], 0, 0, 0);
                        if (si > 0)
                            acc[si - 1][pg] = __builtin_amdgcn_mfma_f32_16x16x32_bf16(afB, bfv, acc[si - 1][pg], 0, 0, 0);
                    }
                    if (a1) {
                        acc[3 + si][pg] = __builtin_amdgcn_mfma_f32_16x16x32_bf16(afC, bfv, acc[3 + si][pg], 0, 0, 0);
                        if (si > 0)
                            acc[2 + si][pg] = __builtin_amdgcn_mfma_f32_16x16x32_bf16(afD, bfv, acc[2 + si][pg], 0, 0, 0);
                    }
                }
            }
            __syncthreads();       // drains vmcnt (stage landed) + lgkm
            cur ^= 1;
        }
    }

    // ---- epilogue: D row = o = q*4+reg, col = pixel = n ----
    #pragma unroll
    for (int st = 0; st < 6; ++st) {
        const int c = st / 3, s0 = st - 3 * c;
        const int g = (R + c) * 3 + s0;
        const size_t obase = ((size_t)b * COUT * NRS + g) * IMG;
        #pragma unroll
        for (int pg = 0; pg < 4; ++pg) {
            int row = th0 + wave * 4 + pg;
            int col = tw0 + n;
            size_t pix = (size_t)row * HW + col;
            #pragma unroll
            for (int r = 0; r < 4; ++r) {
                int o = q * 4 + r;
                out[obase + (size_t)o * NRS * IMG + pix] = acc[st][pg][r];
            }
        }
    }
}

// Fallback: direct-from-x version (R2/R6 structure, 32x16 tile, one r0-column).
__global__ __launch_bounds__(256, 2)
void conv_slow(const float* __restrict__ x, const unsigned short* __restrict__ kc,
               float* __restrict__ out) {
    const int b   = blockIdx.z;
    const int r0  = blockIdx.y;
    const int th0 = (blockIdx.x >> 3) * 32;
    const int tw0 = (blockIdx.x & 7) * 16;

    const int t    = threadIdx.x;
    const int lane = t & 63;
    const int wave = t >> 6;
    const int n    = lane & 15;
    const int q    = lane >> 4;
    const int possel = q >> 1;
    const int half_  = q & 1;

    __shared__ uint4 xs4[(2 * 11520) / 16];
    char* xsc = (char*)xs4;

    int boff[13];
    #pragma unroll
    for (int pp = 0; pp < 13; ++pp) {
        int pos = 2 * pp + possel; if (pos > 24) pos = 24;
        int dx = pos / 5, dy = pos - 5 * dx;
        boff[pp] = half_ * 11520 + dx * 320 + (n + dy) * 16;
    }
    const int aoff = n * 32 + q * 8;

    f32x4 acc[3][8];
    #pragma unroll
    for (int s0 = 0; s0 < 3; ++s0)
        #pragma unroll
        for (int pg = 0; pg < 8; ++pg) acc[s0][pg] = (f32x4){0.f, 0.f, 0.f, 0.f};

    #pragma unroll 1
    for (int i = 0; i < 2; ++i) {
        int rr = r0 + i; if (rr >= 4) rr -= 4;
        #pragma unroll
        for (int ss = 0; ss < 3; ++ss) {
            const int sin_ = rr * 3 + ss;
            const float* xb = x + ((size_t)b * CIN * NRS + sin_) * IMG;

            __syncthreads();
            for (int p = t; p < 720; p += 256) {
                int rl = p / 20, cl = p - rl * 20;
                int hh = th0 + rl - 2, ww = tw0 + cl - 2;
                bool ok = ((unsigned)hh < 128u) && ((unsigned)ww < 128u);
                const float* px = xb + hh * HW + ww;
                unsigned short v[16];
                #pragma unroll
                for (int ic = 0; ic < 16; ++ic) {
                    float f = 0.f;
                    if (ok) f = px[(size_t)ic * ICSTRIDE];
                    v[ic] = f2bf(f);
                }
                uint4 lo, hi;
                lo.x = v[0] | (v[1] << 16);  lo.y = v[2] | (v[3] << 16);
                lo.z = v[4] | (v[5] << 16);  lo.w = v[6] | (v[7] << 16);
                hi.x = v[8] | (v[9] << 16);  hi.y = v[10] | (v[11] << 16);
                hi.z = v[12] | (v[13] << 16); hi.w = v[14] | (v[15] << 16);
                *(uint4*)(xsc + p * 16)         = lo;
                *(uint4*)(xsc + 11520 + p * 16) = hi;
            }
            __syncthreads();

            const unsigned short* kc0 = kc + (size_t)((r0 * 3 + ss) * 4 + 2 * i) * (13 * 512);
            const unsigned short* kc1 = kc + (size_t)((r0 * 3 + ss - 1) * 4 + 2 * i + 1) * (13 * 512);
            const char* wb = xsc + wave * 8 * 320;
            #pragma unroll
            for (int pp = 0; pp < 13; ++pp) {
                bf16x8 af0 = *(const bf16x8*)(kc0 + pp * 512 + aoff);
                bf16x8 af1;
                if (ss > 0) af1 = *(const bf16x8*)(kc1 + pp * 512 + aoff);
                const char* wp = wb + boff[pp];
                #pragma unroll
                for (int pg = 0; pg < 8; ++pg) {
                    bf16x8 bfv = *(const bf16x8*)(wp + pg * 320);
                    acc[ss][pg] = __builtin_amdgcn_mfma_f32_16x16x32_bf16(af0, bfv, acc[ss][pg], 0, 0, 0);
                    if (ss > 0)
                        acc[ss - 1][pg] = __builtin_amdgcn_mfma_f32_16x16x32_bf16(af1, bfv, acc[ss - 1][pg], 0, 0, 0);
                }
            }
        }
    }

    #pragma unroll
    for (int s0 = 0; s0 < 3; ++s0) {
        const size_t obase = ((size_t)b * COUT * NRS + (r0 * 3 + s0)) * IMG;
        #pragma unroll
        for (int pg = 0; pg < 8; ++pg) {
            int row = th0 + wave * 8 + pg;
            int col = tw0 + n;
            size_t pix = (size_t)row * HW + col;
            #pragma unroll
            for (int r = 0; r < 4; ++r) {
                int o = q * 4 + r;
                out[obase + (size_t)o * NRS * IMG + pix] = acc[s0][pg][r];
            }
        }
    }
}

extern "C" void kernel_launch(void* const* d_in, const int* in_sizes, int n_in,
                              void* d_out, int out_size, void* d_ws, size_t ws_size,
                              hipStream_t stream) {
    const float* x      = (const float*)d_in[0];
    const float* weight = (const float*)d_in[1];
    const float* basis  = (const float*)d_in[2];
    float* out = (float*)d_out;
    unsigned short* kc = (unsigned short*)d_ws;            // 639 KB

    build_kc<<<dim3((12 * 4 * 13 * 16 * 32 + 255) / 256), dim3(256), 0, stream>>>(weight, basis, kc);

    const size_t xbf_off = 655360;                         // 640 KB, 16B-aligned
    const size_t xbf_bytes = (size_t)8 * 12 * PADW * PADW * 32;   // 53.5 MB
    if (ws_size >= xbf_off + xbf_bytes) {
        unsigned short* xbf = (unsigned short*)((char*)d_ws + xbf_off);
        cvt_pad<<<dim3((8 * 12 * PADW * PADW + 255) / 256), dim3(256), 0, stream>>>(x, xbf);
        conv_fast<<<dim3(64, 2, 8), dim3(256), 0, stream>>>(xbf, kc, out);
    } else {
        conv_slow<<<dim3(32, 4, 8), dim3(256), 0, stream>>>(x, kc, out);
    }
}

// Round 8
// 279.491 us; speedup vs baseline: 1.1635x; 1.1635x over previous
//
#include <hip/hip_runtime.h>

// SESConv via implicit GEMM on bf16 MFMA (gfx950).
// out[b,o,g,h,w] = sum_{rbase valid, ic, xk, yk} Kc[g,rbase,pos,ic,o] * X[b,ic,src(g,rbase), h+xk-2, w+yk-2]
// Kc[...] = sum_f weight[o,ic,rbase,f] * basis[f,g,xk,yk]
// x: (8,16,12,128,128) f32; weight: (16,16,4,9) f32; basis: (9,12,5,5) f32; out: (8,16,12,128,128) f32
//
// R8: R6 (best, 88us: DMA staging, zero-conflict 320B-row LDS layout, r0-column
// 2-user slice sharing, 32x16 tile) + __launch_bounds__(256,3). R6 was register-
// bound to 2 waves/SIMD (acc 96 AGPR + 116 arch = 212); LDS (49KB) already fits
// 3 blocks/CU. Cap regalloc at 170 total -> 3 waves/SIMD: +50% latency-hiding wave
// pool over the ~50us LDS-issue floor. R7's thin-phase restructure (157us) and R4's
// thin-wave restructure (96us) both regressed: keep the fat 6-phase shape.

#define NRS 12
#define CIN 16
#define COUT 16
#define HW 128
#define IMG (HW*HW)
#define ICSTRIDE (NRS*IMG)        // x stride between input channels (floats)

// fast-path geometry: LDS slice = [half(2)][rl(36)][cl(20)] 16B chunks, rows 320B
#define HALO_H 36
#define HALO_W 20
#define ROWB 320                  // bytes per halo row per half (20 px * 16 B)
#define HALFB 11520               // 720 chunks * 16 B per ic-half
#define NCHUNK 1440               // 36*20*2 16B-chunks per slice
#define BUFB 24576                // 1536 chunk slots * 16 B (4 waves * 6 * 64); 96 pad
#define PADW 132
#define PADROWB (PADW*32)         // 4224 B per padded row (132 px * 32 B)

typedef __bf16 bf16x8 __attribute__((ext_vector_type(8)));
typedef float  f32x4  __attribute__((ext_vector_type(4)));

__device__ __forceinline__ unsigned short f2bf(float f) {
    unsigned u = __builtin_bit_cast(unsigned, f);
    u += 0x7fffu + ((u >> 16) & 1u);          // round-nearest-even
    return (unsigned short)(u >> 16);
}

// A-panel: [g(12)][rbase(4)][pp(13)][o(16)][k(32)] bf16, k = possel*16 + ic, pos = 2*pp+possel
// pos==25 -> 0 (pad). 319488 elems = 639 KB.
__global__ void build_kc(const float* __restrict__ wgt, const float* __restrict__ basis,
                         unsigned short* __restrict__ kc) {
    int idx = blockIdx.x * 256 + threadIdx.x;
    const int total = 12 * 4 * 13 * 16 * 32;   // 319488
    if (idx >= total) return;
    int k  = idx & 31;
    int possel = k >> 4, ic = k & 15;
    int o  = (idx >> 5) & 15;
    int t2 = idx >> 9;
    int pp = t2 % 13;
    int gr = t2 / 13;
    int rbase = gr & 3, g = gr >> 2;
    int pos = 2 * pp + possel;
    float s = 0.f;
    if (pos < 25) {
        int xk = pos / 5, yk = pos - 5 * xk;
        #pragma unroll
        for (int f = 0; f < 9; ++f)
            s = fmaf(wgt[((o * CIN + ic) * 4 + rbase) * 9 + f],
                     basis[((f * NRS + g) * 5 + xk) * 5 + yk], s);
    }
    kc[idx] = f2bf(s);
}

// Pre-pass: x (b,ic,s,h,w) f32 -> xbf[b][s][hp 132][wp 132][ic 16] bf16, 2-px zero border.
__global__ void cvt_pad(const float* __restrict__ x, unsigned short* __restrict__ xbf) {
    int idx = blockIdx.x * 256 + threadIdx.x;
    const int total = 8 * 12 * PADW * PADW;    // 1,672,704
    if (idx >= total) return;
    int wp = idx % PADW;
    int t1 = idx / PADW;
    int hp = t1 % PADW;
    int bs = t1 / PADW;                        // b*12 + s
    int s  = bs % 12, bb = bs / 12;
    int h = hp - 2, w = wp - 2;
    bool ok = ((unsigned)h < 128u) && ((unsigned)w < 128u);
    const float* px = x + ((size_t)bb * 192 + s) * IMG + h * HW + w;   // +ic*12*IMG
    unsigned short v[16];
    #pragma unroll
    for (int ic = 0; ic < 16; ++ic) {
        float f = 0.f;
        if (ok) f = px[(size_t)ic * ICSTRIDE];
        v[ic] = f2bf(f);
    }
    uint4 lo, hi;
    lo.x = v[0] | (v[1] << 16);  lo.y = v[2] | (v[3] << 16);
    lo.z = v[4] | (v[5] << 16);  lo.w = v[6] | (v[7] << 16);
    hi.x = v[8] | (v[9] << 16);  hi.y = v[10] | (v[11] << 16);
    hi.z = v[12] | (v[13] << 16); hi.w = v[14] | (v[15] << 16);
    *(uint4*)(xbf + (size_t)idx * 16)     = lo;
    *(uint4*)(xbf + (size_t)idx * 16 + 8) = hi;
}

// issue one slice's staging DMA: soff recomputed at point of use (shorter live ranges)
__device__ __forceinline__ void stage_slice(const char* sb, char* lb, int wave, int lane) {
    #pragma unroll
    for (int j = 0; j < 6; ++j) {
        int c = wave * 384 + j * 64 + lane;
        int soff = 0;
        if (c < NCHUNK) {
            int hf = c / 720, p = c - hf * 720;
            int rl = p / 20, cl = p - rl * 20;
            soff = rl * PADROWB + cl * 32 + hf * 16;
        }
        __builtin_amdgcn_global_load_lds(
            (const __attribute__((address_space(1))) void*)(sb + soff),
            (__attribute__((address_space(3))) void*)(lb + j * 1024), 16, 0, 0);
    }
}

__global__ __launch_bounds__(256, 3)
void conv_fast(const unsigned short* __restrict__ xbf, const unsigned short* __restrict__ kc,
               float* __restrict__ out) {
    const int b   = blockIdx.z;
    const int r0  = blockIdx.y;                    // 0..3 (r0-column of 3 g's)
    const int th0 = (blockIdx.x >> 3) * 32;        // 4 row-tiles of 32
    const int tw0 = (blockIdx.x & 7) * 16;         // 8 col-tiles of 16

    const int t    = threadIdx.x;
    const int lane = t & 63;
    const int wave = t >> 6;                       // 0..3, owns 8 output rows
    const int n    = lane & 15;        // MFMA N index
    const int q    = lane >> 4;
    const int possel = q >> 1;
    const int half_  = q & 1;

    __shared__ uint4 xs4[(2 * BUFB) / 16];         // 49152 B, double-buffered
    char* xsc = (char*)xs4;

    // B-fragment byte offsets per K-step (zero-conflict family: 320B rows, 16B/lane)
    int boff[13];
    #pragma unroll
    for (int pp = 0; pp < 13; ++pp) {
        int pos = 2 * pp + possel; if (pos > 24) pos = 24;   // pad tap reads tap 24; A=0 there
        int dx = pos / 5, dy = pos - 5 * dx;
        boff[pp] = half_ * HALFB + dx * ROWB + (n + dy) * 16;
    }
    const int aoff = n * 32 + q * 8;               // A-frag: o*32 + q*8 (ushort elems)

    f32x4 acc[3][8];
    #pragma unroll
    for (int s0 = 0; s0 < 3; ++s0)
        #pragma unroll
        for (int pg = 0; pg < 8; ++pg) acc[s0][pg] = (f32x4){0.f, 0.f, 0.f, 0.f};

    const char* xb0 = (const char*)xbf;
    const size_t tileoff = ((size_t)th0 * PADW + tw0) * 32;

    // prologue: stage slice (i=0, ss=0): sin = r0*3
    stage_slice(xb0 + ((size_t)(b * 12 + r0 * 3) * PADW * PADW) * 32 + tileoff,
                xsc + wave * 6144, wave, lane);
    __syncthreads();
    int cur = 0;

    #pragma unroll 1
    for (int i = 0; i < 2; ++i) {                  // rolled: acc index never depends on i
        int rr = r0 + i; if (rr >= 4) rr -= 4;
        int rrn = rr + 1; if (rrn >= 4) rrn -= 4;
        #pragma unroll
        for (int ss = 0; ss < 3; ++ss) {           // unrolled: static acc[ss]/acc[ss-1]
            // ---- issue async stage of next slice into buf[cur^1] ----
            if (i == 0 || ss < 2) {
                int sin_next = (ss < 2) ? (rr * 3 + ss + 1) : (rrn * 3);
                stage_slice(xb0 + ((size_t)(b * 12 + sin_next) * PADW * PADW) * 32 + tileoff,
                            xsc + (cur ^ 1) * BUFB + wave * 6144, wave, lane);
            }

            // ---- GEMM over current slice: 13 K-steps x 8 pixel groups, 1-2 users ----
            // user j=0: g = r0*3+ss,   rbase = 2i   -> acc[ss]
            // user j=1: g = r0*3+ss-1, rbase = 2i+1 -> acc[ss-1]   (only ss>0)
            const unsigned short* kc0 = kc + (size_t)((r0 * 3 + ss) * 4 + 2 * i) * (13 * 512);
            const char* wb = xsc + cur * BUFB + wave * 8 * ROWB;
            if (ss > 0) {
                const unsigned short* kc1 = kc + (size_t)((r0 * 3 + ss - 1) * 4 + 2 * i + 1) * (13 * 512);
                #pragma unroll
                for (int pp = 0; pp < 13; ++pp) {
                    bf16x8 af0 = *(const bf16x8*)(kc0 + pp * 512 + aoff);
                    bf16x8 af1 = *(const bf16x8*)(kc1 + pp * 512 + aoff);
                    const char* wp = wb + boff[pp];
                    #pragma unroll
                    for (int pg = 0; pg < 8; ++pg) {
                        bf16x8 bfv = *(const bf16x8*)(wp + pg * ROWB);
                        acc[ss][pg]     = __builtin_amdgcn_mfma_f32_16x16x32_bf16(af0, bfv, acc[ss][pg], 0, 0, 0);
                        acc[ss - 1][pg] = __builtin_amdgcn_mfma_f32_16x16x32_bf16(af1, bfv, acc[ss - 1][pg], 0, 0, 0);
                    }
                }
            } else {
                #pragma unroll
                for (int pp = 0; pp < 13; ++pp) {
                    bf16x8 af0 = *(const bf16x8*)(kc0 + pp * 512 + aoff);
                    const char* wp = wb + boff[pp];
                    #pragma unroll
                    for (int pg = 0; pg < 8; ++pg) {
                        bf16x8 bfv = *(const bf16x8*)(wp + pg * ROWB);
                        acc[ss][pg] = __builtin_amdgcn_mfma_f32_16x16x32_bf16(af0, bfv, acc[ss][pg], 0, 0, 0);
                    }
                }
            }
            __syncthreads();       // drains vmcnt (stage landed) + lgkm
            cur ^= 1;
        }
    }

    // ---- epilogue: D row = o = q*4+reg, col = pixel = n ----
    #pragma unroll
    for (int s0 = 0; s0 < 3; ++s0) {
        const size_t obase = ((size_t)b * COUT * NRS + (r0 * 3 + s0)) * IMG;
        #pragma unroll
        for (int pg = 0; pg < 8; ++pg) {
            int row = th0 + wave * 8 + pg;
            int col = tw0 + n;
            size_t pix = (size_t)row * HW + col;
            #pragma unroll
            for (int r = 0; r < 4; ++r) {
                int o = q * 4 + r;
                out[obase + (size_t)o * NRS * IMG + pix] = acc[s0][pg][r];
            }
        }
    }
}

// Fallback: direct-from-x version (R2/R6 structure), used only if workspace can't hold xbf.
__global__ __launch_bounds__(256, 2)
void conv_slow(const float* __restrict__ x, const unsigned short* __restrict__ kc,
               float* __restrict__ out) {
    const int b   = blockIdx.z;
    const int r0  = blockIdx.y;
    const int th0 = (blockIdx.x >> 3) * 32;
    const int tw0 = (blockIdx.x & 7) * 16;

    const int t    = threadIdx.x;
    const int lane = t & 63;
    const int wave = t >> 6;
    const int n    = lane & 15;
    const int q    = lane >> 4;
    const int possel = q >> 1;
    const int half_  = q & 1;

    __shared__ uint4 xs4[(2 * HALFB) / 16];
    char* xsc = (char*)xs4;

    int boff[13];
    #pragma unroll
    for (int pp = 0; pp < 13; ++pp) {
        int pos = 2 * pp + possel; if (pos > 24) pos = 24;
        int dx = pos / 5, dy = pos - 5 * dx;
        boff[pp] = half_ * HALFB + dx * ROWB + (n + dy) * 16;
    }
    const int aoff = n * 32 + q * 8;

    f32x4 acc[3][8];
    #pragma unroll
    for (int s0 = 0; s0 < 3; ++s0)
        #pragma unroll
        for (int pg = 0; pg < 8; ++pg) acc[s0][pg] = (f32x4){0.f, 0.f, 0.f, 0.f};

    #pragma unroll 1
    for (int i = 0; i < 2; ++i) {
        int rr = r0 + i; if (rr >= 4) rr -= 4;
        #pragma unroll
        for (int ss = 0; ss < 3; ++ss) {
            const int sin_ = rr * 3 + ss;
            const float* xb = x + ((size_t)b * CIN * NRS + sin_) * IMG;

            __syncthreads();
            for (int p = t; p < 720; p += 256) {
                int rl = p / HALO_W, cl = p - rl * HALO_W;
                int hh = th0 + rl - 2, ww = tw0 + cl - 2;
                bool ok = ((unsigned)hh < 128u) && ((unsigned)ww < 128u);
                const float* px = xb + hh * HW + ww;
                unsigned short v[16];
                #pragma unroll
                for (int ic = 0; ic < 16; ++ic) {
                    float f = 0.f;
                    if (ok) f = px[(size_t)ic * ICSTRIDE];
                    v[ic] = f2bf(f);
                }
                uint4 lo, hi;
                lo.x = v[0] | (v[1] << 16);  lo.y = v[2] | (v[3] << 16);
                lo.z = v[4] | (v[5] << 16);  lo.w = v[6] | (v[7] << 16);
                hi.x = v[8] | (v[9] << 16);  hi.y = v[10] | (v[11] << 16);
                hi.z = v[12] | (v[13] << 16); hi.w = v[14] | (v[15] << 16);
                *(uint4*)(xsc + p * 16)         = lo;
                *(uint4*)(xsc + HALFB + p * 16) = hi;
            }
            __syncthreads();

            const unsigned short* kc0 = kc + (size_t)((r0 * 3 + ss) * 4 + 2 * i) * (13 * 512);
            const unsigned short* kc1 = kc + (size_t)((r0 * 3 + ss - 1) * 4 + 2 * i + 1) * (13 * 512);
            const char* wb = xsc + wave * 8 * ROWB;
            #pragma unroll
            for (int pp = 0; pp < 13; ++pp) {
                bf16x8 af0 = *(const bf16x8*)(kc0 + pp * 512 + aoff);
                bf16x8 af1;
                if (ss > 0) af1 = *(const bf16x8*)(kc1 + pp * 512 + aoff);
                const char* wp = wb + boff[pp];
                #pragma unroll
                for (int pg = 0; pg < 8; ++pg) {
                    bf16x8 bfv = *(const bf16x8*)(wp + pg * ROWB);
                    acc[ss][pg] = __builtin_amdgcn_mfma_f32_16x16x32_bf16(af0, bfv, acc[ss][pg], 0, 0, 0);
                    if (ss > 0)
                        acc[ss - 1][pg] = __builtin_amdgcn_mfma_f32_16x16x32_bf16(af1, bfv, acc[ss - 1][pg], 0, 0, 0);
                }
            }
        }
    }

    #pragma unroll
    for (int s0 = 0; s0 < 3; ++s0) {
        const size_t obase = ((size_t)b * COUT * NRS + (r0 * 3 + s0)) * IMG;
        #pragma unroll
        for (int pg = 0; pg < 8; ++pg) {
            int row = th0 + wave * 8 + pg;
            int col = tw0 + n;
            size_t pix = (size_t)row * HW + col;
            #pragma unroll
            for (int r = 0; r < 4; ++r) {
                int o = q * 4 + r;
                out[obase + (size_t)o * NRS * IMG + pix] = acc[s0][pg][r];
            }
        }
    }
}

extern "C" void kernel_launch(void* const* d_in, const int* in_sizes, int n_in,
                              void* d_out, int out_size, void* d_ws, size_t ws_size,
                              hipStream_t stream) {
    const float* x      = (const float*)d_in[0];
    const float* weight = (const float*)d_in[1];
    const float* basis  = (const float*)d_in[2];
    float* out = (float*)d_out;
    unsigned short* kc = (unsigned short*)d_ws;            // 639 KB

    build_kc<<<dim3((12 * 4 * 13 * 16 * 32 + 255) / 256), dim3(256), 0, stream>>>(weight, basis, kc);

    const size_t xbf_off = 655360;                         // 640 KB, 16B-aligned
    const size_t xbf_bytes = (size_t)8 * 12 * PADW * PADW * 32;   // 53.5 MB
    if (ws_size >= xbf_off + xbf_bytes) {
        unsigned short* xbf = (unsigned short*)((char*)d_ws + xbf_off);
        cvt_pad<<<dim3((8 * 12 * PADW * PADW + 255) / 256), dim3(256), 0, stream>>>(x, xbf);
        conv_fast<<<dim3(32, 4, 8), dim3(256), 0, stream>>>(xbf, kc, out);
    } else {
        conv_slow<<<dim3(32, 4, 8), dim3(256), 0, stream>>>(x, kc, out);
    }
}

// Round 9
// 254.184 us; speedup vs baseline: 1.2793x; 1.0996x over previous
//
#include <hip/hip_runtime.h>

// SESConv via implicit GEMM on bf16 MFMA (gfx950).
// out[b,o,g,h,w] = sum_{rbase valid, ic, xk, yk} Kc[g,rbase,pos,ic,o] * X[b,ic,src(g,rbase), h+xk-2, w+yk-2]
// Kc[...] = sum_f weight[o,ic,rbase,f] * basis[f,g,xk,yk]
// x: (8,16,12,128,128) f32; weight: (16,16,4,9) f32; basis: (9,12,5,5) f32; out: (8,16,12,128,128) f32
//
// R9: R6 (best, 88us) + explicit 3-deep A-fragment software pipeline. R6's residual
// gap (88 vs ~49us LDS floor): af global loads from kc interleave the GEMM at every
// pp; in-order vmcnt exposes L2/L3 latency at each pp boundary with only 2 waves/SIMD
// of TLP. Fix: rotate af through 3 static slots (pp unrolled -> static indexing),
// prefetch pp+3 before pp's MFMAs; prologue afs issued BEFORE the stage DMA so af
// waits never drain the stage. R8's (256,3) spilled 57MB (AGPR acc can't shrink) ->
// bounds back to (256,2).

#define NRS 12
#define CIN 16
#define COUT 16
#define HW 128
#define IMG (HW*HW)
#define ICSTRIDE (NRS*IMG)        // x stride between input channels (floats)

// fast-path geometry: LDS slice = [half(2)][rl(36)][cl(20)] 16B chunks, rows 320B
#define HALO_H 36
#define HALO_W 20
#define ROWB 320                  // bytes per halo row per half (20 px * 16 B)
#define HALFB 11520               // 720 chunks * 16 B per ic-half
#define NCHUNK 1440               // 36*20*2 16B-chunks per slice
#define BUFB 24576                // 1536 chunk slots * 16 B (4 waves * 6 * 64); 96 pad
#define PADW 132
#define PADROWB (PADW*32)         // 4224 B per padded row (132 px * 32 B)

typedef __bf16 bf16x8 __attribute__((ext_vector_type(8)));
typedef float  f32x4  __attribute__((ext_vector_type(4)));

__device__ __forceinline__ unsigned short f2bf(float f) {
    unsigned u = __builtin_bit_cast(unsigned, f);
    u += 0x7fffu + ((u >> 16) & 1u);          // round-nearest-even
    return (unsigned short)(u >> 16);
}

// A-panel: [g(12)][rbase(4)][pp(13)][o(16)][k(32)] bf16, k = possel*16 + ic, pos = 2*pp+possel
// pos==25 -> 0 (pad). 319488 elems = 639 KB.
__global__ void build_kc(const float* __restrict__ wgt, const float* __restrict__ basis,
                         unsigned short* __restrict__ kc) {
    int idx = blockIdx.x * 256 + threadIdx.x;
    const int total = 12 * 4 * 13 * 16 * 32;   // 319488
    if (idx >= total) return;
    int k  = idx & 31;
    int possel = k >> 4, ic = k & 15;
    int o  = (idx >> 5) & 15;
    int t2 = idx >> 9;
    int pp = t2 % 13;
    int gr = t2 / 13;
    int rbase = gr & 3, g = gr >> 2;
    int pos = 2 * pp + possel;
    float s = 0.f;
    if (pos < 25) {
        int xk = pos / 5, yk = pos - 5 * xk;
        #pragma unroll
        for (int f = 0; f < 9; ++f)
            s = fmaf(wgt[((o * CIN + ic) * 4 + rbase) * 9 + f],
                     basis[((f * NRS + g) * 5 + xk) * 5 + yk], s);
    }
    kc[idx] = f2bf(s);
}

// Pre-pass: x (b,ic,s,h,w) f32 -> xbf[b][s][hp 132][wp 132][ic 16] bf16, 2-px zero border.
__global__ void cvt_pad(const float* __restrict__ x, unsigned short* __restrict__ xbf) {
    int idx = blockIdx.x * 256 + threadIdx.x;
    const int total = 8 * 12 * PADW * PADW;    // 1,672,704
    if (idx >= total) return;
    int wp = idx % PADW;
    int t1 = idx / PADW;
    int hp = t1 % PADW;
    int bs = t1 / PADW;                        // b*12 + s
    int s  = bs % 12, bb = bs / 12;
    int h = hp - 2, w = wp - 2;
    bool ok = ((unsigned)h < 128u) && ((unsigned)w < 128u);
    const float* px = x + ((size_t)bb * 192 + s) * IMG + h * HW + w;   // +ic*12*IMG
    unsigned short v[16];
    #pragma unroll
    for (int ic = 0; ic < 16; ++ic) {
        float f = 0.f;
        if (ok) f = px[(size_t)ic * ICSTRIDE];
        v[ic] = f2bf(f);
    }
    uint4 lo, hi;
    lo.x = v[0] | (v[1] << 16);  lo.y = v[2] | (v[3] << 16);
    lo.z = v[4] | (v[5] << 16);  lo.w = v[6] | (v[7] << 16);
    hi.x = v[8] | (v[9] << 16);  hi.y = v[10] | (v[11] << 16);
    hi.z = v[12] | (v[13] << 16); hi.w = v[14] | (v[15] << 16);
    *(uint4*)(xbf + (size_t)idx * 16)     = lo;
    *(uint4*)(xbf + (size_t)idx * 16 + 8) = hi;
}

// issue one slice's staging DMA
__device__ __forceinline__ void stage_slice(const char* sb, char* lb, int wave, int lane) {
    #pragma unroll
    for (int j = 0; j < 6; ++j) {
        int c = wave * 384 + j * 64 + lane;
        int soff = 0;
        if (c < NCHUNK) {
            int hf = c / 720, p = c - hf * 720;
            int rl = p / 20, cl = p - rl * 20;
            soff = rl * PADROWB + cl * 32 + hf * 16;
        }
        __builtin_amdgcn_global_load_lds(
            (const __attribute__((address_space(1))) void*)(sb + soff),
            (__attribute__((address_space(3))) void*)(lb + j * 1024), 16, 0, 0);
    }
}

__global__ __launch_bounds__(256, 2)
void conv_fast(const unsigned short* __restrict__ xbf, const unsigned short* __restrict__ kc,
               float* __restrict__ out) {
    const int b   = blockIdx.z;
    const int r0  = blockIdx.y;                    // 0..3 (r0-column of 3 g's)
    const int th0 = (blockIdx.x >> 3) * 32;        // 4 row-tiles of 32
    const int tw0 = (blockIdx.x & 7) * 16;         // 8 col-tiles of 16

    const int t    = threadIdx.x;
    const int lane = t & 63;
    const int wave = t >> 6;                       // 0..3, owns 8 output rows
    const int n    = lane & 15;        // MFMA N index
    const int q    = lane >> 4;
    const int possel = q >> 1;
    const int half_  = q & 1;

    __shared__ uint4 xs4[(2 * BUFB) / 16];         // 49152 B, double-buffered
    char* xsc = (char*)xs4;

    // B-fragment byte offsets per K-step (zero-conflict family: 320B rows, 16B/lane)
    int boff[13];
    #pragma unroll
    for (int pp = 0; pp < 13; ++pp) {
        int pos = 2 * pp + possel; if (pos > 24) pos = 24;   // pad tap reads tap 24; A=0 there
        int dx = pos / 5, dy = pos - 5 * dx;
        boff[pp] = half_ * HALFB + dx * ROWB + (n + dy) * 16;
    }
    const int aoff = n * 32 + q * 8;               // A-frag: o*32 + q*8 (ushort elems)

    f32x4 acc[3][8];
    #pragma unroll
    for (int s0 = 0; s0 < 3; ++s0)
        #pragma unroll
        for (int pg = 0; pg < 8; ++pg) acc[s0][pg] = (f32x4){0.f, 0.f, 0.f, 0.f};

    const char* xb0 = (const char*)xbf;
    const size_t tileoff = ((size_t)th0 * PADW + tw0) * 32;

    // prologue: stage slice (i=0, ss=0): sin = r0*3
    stage_slice(xb0 + ((size_t)(b * 12 + r0 * 3) * PADW * PADW) * 32 + tileoff,
                xsc + wave * 6144, wave, lane);
    __syncthreads();
    int cur = 0;

    #pragma unroll 1
    for (int i = 0; i < 2; ++i) {                  // rolled: acc index never depends on i
        int rr = r0 + i; if (rr >= 4) rr -= 4;
        int rrn = rr + 1; if (rrn >= 4) rrn -= 4;
        #pragma unroll
        for (int ss = 0; ss < 3; ++ss) {           // unrolled: static acc[ss]/acc[ss-1]
            const unsigned short* kc0 = kc + (size_t)((r0 * 3 + ss) * 4 + 2 * i) * (13 * 512);
            const unsigned short* kc1 = kc + (size_t)((r0 * 3 + ss - 1) * 4 + 2 * i + 1) * (13 * 512);

            // ---- af prologue: 3-deep pipeline fill, issued BEFORE the stage DMA so
            //      af vmcnt waits never force a DMA drain (in-order vmcnt) ----
            bf16x8 A0[3], A1[3];
            #pragma unroll
            for (int jp = 0; jp < 3; ++jp) {
                A0[jp] = *(const bf16x8*)(kc0 + jp * 512 + aoff);
                if (ss > 0) A1[jp] = *(const bf16x8*)(kc1 + jp * 512 + aoff);
            }

            // ---- issue async stage of next slice into buf[cur^1] ----
            if (i == 0 || ss < 2) {
                int sin_next = (ss < 2) ? (rr * 3 + ss + 1) : (rrn * 3);
                stage_slice(xb0 + ((size_t)(b * 12 + sin_next) * PADW * PADW) * 32 + tileoff,
                            xsc + (cur ^ 1) * BUFB + wave * 6144, wave, lane);
            }

            // ---- GEMM over current slice: 13 K-steps x 8 pixel groups, 1-2 users ----
            // user j=0: g = r0*3+ss,   rbase = 2i   -> acc[ss]
            // user j=1: g = r0*3+ss-1, rbase = 2i+1 -> acc[ss-1]   (only ss>0)
            const char* wb = xsc + cur * BUFB + wave * 8 * ROWB;
            #pragma unroll
            for (int pp = 0; pp < 13; ++pp) {
                const int slot = pp % 3;           // static after unroll
                bf16x8 af0 = A0[slot];
                bf16x8 af1;
                if (ss > 0) af1 = A1[slot];
                if (pp + 3 < 13) {                 // prefetch pp+3 into freed slot
                    A0[slot] = *(const bf16x8*)(kc0 + (pp + 3) * 512 + aoff);
                    if (ss > 0) A1[slot] = *(const bf16x8*)(kc1 + (pp + 3) * 512 + aoff);
                }
                const char* wp = wb + boff[pp];
                if (ss > 0) {
                    #pragma unroll
                    for (int pg = 0; pg < 8; ++pg) {
                        bf16x8 bfv = *(const bf16x8*)(wp + pg * ROWB);
                        acc[ss][pg]     = __builtin_amdgcn_mfma_f32_16x16x32_bf16(af0, bfv, acc[ss][pg], 0, 0, 0);
                        acc[ss - 1][pg] = __builtin_amdgcn_mfma_f32_16x16x32_bf16(af1, bfv, acc[ss - 1][pg], 0, 0, 0);
                    }
                } else {
                    #pragma unroll
                    for (int pg = 0; pg < 8; ++pg) {
                        bf16x8 bfv = *(const bf16x8*)(wp + pg * ROWB);
                        acc[ss][pg] = __builtin_amdgcn_mfma_f32_16x16x32_bf16(af0, bfv, acc[ss][pg], 0, 0, 0);
                    }
                }
            }
            __syncthreads();       // drains vmcnt (stage landed) + lgkm
            cur ^= 1;
        }
    }

    // ---- epilogue: D row = o = q*4+reg, col = pixel = n ----
    #pragma unroll
    for (int s0 = 0; s0 < 3; ++s0) {
        const size_t obase = ((size_t)b * COUT * NRS + (r0 * 3 + s0)) * IMG;
        #pragma unroll
        for (int pg = 0; pg < 8; ++pg) {
            int row = th0 + wave * 8 + pg;
            int col = tw0 + n;
            size_t pix = (size_t)row * HW + col;
            #pragma unroll
            for (int r = 0; r < 4; ++r) {
                int o = q * 4 + r;
                out[obase + (size_t)o * NRS * IMG + pix] = acc[s0][pg][r];
            }
        }
    }
}

// Fallback: direct-from-x version (R2/R6 structure), used only if workspace can't hold xbf.
__global__ __launch_bounds__(256, 2)
void conv_slow(const float* __restrict__ x, const unsigned short* __restrict__ kc,
               float* __restrict__ out) {
    const int b   = blockIdx.z;
    const int r0  = blockIdx.y;
    const int th0 = (blockIdx.x >> 3) * 32;
    const int tw0 = (blockIdx.x & 7) * 16;

    const int t    = threadIdx.x;
    const int lane = t & 63;
    const int wave = t >> 6;
    const int n    = lane & 15;
    const int q    = lane >> 4;
    const int possel = q >> 1;
    const int half_  = q & 1;

    __shared__ uint4 xs4[(2 * HALFB) / 16];
    char* xsc = (char*)xs4;

    int boff[13];
    #pragma unroll
    for (int pp = 0; pp < 13; ++pp) {
        int pos = 2 * pp + possel; if (pos > 24) pos = 24;
        int dx = pos / 5, dy = pos - 5 * dx;
        boff[pp] = half_ * HALFB + dx * ROWB + (n + dy) * 16;
    }
    const int aoff = n * 32 + q * 8;

    f32x4 acc[3][8];
    #pragma unroll
    for (int s0 = 0; s0 < 3; ++s0)
        #pragma unroll
        for (int pg = 0; pg < 8; ++pg) acc[s0][pg] = (f32x4){0.f, 0.f, 0.f, 0.f};

    #pragma unroll 1
    for (int i = 0; i < 2; ++i) {
        int rr = r0 + i; if (rr >= 4) rr -= 4;
        #pragma unroll
        for (int ss = 0; ss < 3; ++ss) {
            const int sin_ = rr * 3 + ss;
            const float* xb = x + ((size_t)b * CIN * NRS + sin_) * IMG;

            __syncthreads();
            for (int p = t; p < 720; p += 256) {
                int rl = p / HALO_W, cl = p - rl * HALO_W;
                int hh = th0 + rl - 2, ww = tw0 + cl - 2;
                bool ok = ((unsigned)hh < 128u) && ((unsigned)ww < 128u);
                const float* px = xb + hh * HW + ww;
                unsigned short v[16];
                #pragma unroll
                for (int ic = 0; ic < 16; ++ic) {
                    float f = 0.f;
                    if (ok) f = px[(size_t)ic * ICSTRIDE];
                    v[ic] = f2bf(f);
                }
                uint4 lo, hi;
                lo.x = v[0] | (v[1] << 16);  lo.y = v[2] | (v[3] << 16);
                lo.z = v[4] | (v[5] << 16);  lo.w = v[6] | (v[7] << 16);
                hi.x = v[8] | (v[9] << 16);  hi.y = v[10] | (v[11] << 16);
                hi.z = v[12] | (v[13] << 16); hi.w = v[14] | (v[15] << 16);
                *(uint4*)(xsc + p * 16)         = lo;
                *(uint4*)(xsc + HALFB + p * 16) = hi;
            }
            __syncthreads();

            const unsigned short* kc0 = kc + (size_t)((r0 * 3 + ss) * 4 + 2 * i) * (13 * 512);
            const unsigned short* kc1 = kc + (size_t)((r0 * 3 + ss - 1) * 4 + 2 * i + 1) * (13 * 512);
            const char* wb = xsc + wave * 8 * ROWB;
            #pragma unroll
            for (int pp = 0; pp < 13; ++pp) {
                bf16x8 af0 = *(const bf16x8*)(kc0 + pp * 512 + aoff);
                bf16x8 af1;
                if (ss > 0) af1 = *(const bf16x8*)(kc1 + pp * 512 + aoff);
                const char* wp = wb + boff[pp];
                #pragma unroll
                for (int pg = 0; pg < 8; ++pg) {
                    bf16x8 bfv = *(const bf16x8*)(wp + pg * ROWB);
                    acc[ss][pg] = __builtin_amdgcn_mfma_f32_16x16x32_bf16(af0, bfv, acc[ss][pg], 0, 0, 0);
                    if (ss > 0)
                        acc[ss - 1][pg] = __builtin_amdgcn_mfma_f32_16x16x32_bf16(af1, bfv, acc[ss - 1][pg], 0, 0, 0);
                }
            }
        }
    }

    #pragma unroll
    for (int s0 = 0; s0 < 3; ++s0) {
        const size_t obase = ((size_t)b * COUT * NRS + (r0 * 3 + s0)) * IMG;
        #pragma unroll
        for (int pg = 0; pg < 8; ++pg) {
            int row = th0 + wave * 8 + pg;
            int col = tw0 + n;
            size_t pix = (size_t)row * HW + col;
            #pragma unroll
            for (int r = 0; r < 4; ++r) {
                int o = q * 4 + r;
                out[obase + (size_t)o * NRS * IMG + pix] = acc[s0][pg][r];
            }
        }
    }
}

extern "C" void kernel_launch(void* const* d_in, const int* in_sizes, int n_in,
                              void* d_out, int out_size, void* d_ws, size_t ws_size,
                              hipStream_t stream) {
    const float* x      = (const float*)d_in[0];
    const float* weight = (const float*)d_in[1];
    const float* basis  = (const float*)d_in[2];
    float* out = (float*)d_out;
    unsigned short* kc = (unsigned short*)d_ws;            // 639 KB

    build_kc<<<dim3((12 * 4 * 13 * 16 * 32 + 255) / 256), dim3(256), 0, stream>>>(weight, basis, kc);

    const size_t xbf_off = 655360;                         // 640 KB, 16B-aligned
    const size_t xbf_bytes = (size_t)8 * 12 * PADW * PADW * 32;   // 53.5 MB
    if (ws_size >= xbf_off + xbf_bytes) {
        unsigned short* xbf = (unsigned short*)((char*)d_ws + xbf_off);
        cvt_pad<<<dim3((8 * 12 * PADW * PADW + 255) / 256), dim3(256), 0, stream>>>(x, xbf);
        conv_fast<<<dim3(32, 4, 8), dim3(256), 0, stream>>>(xbf, kc, out);
    } else {
        conv_slow<<<dim3(32, 4, 8), dim3(256), 0, stream>>>(x, kc, out);
    }
}

// Round 10
// 253.192 us; speedup vs baseline: 1.2843x; 1.0039x over previous
//
#include <hip/hip_runtime.h>

// SESConv via implicit GEMM on bf16 MFMA (gfx950).
// out[b,o,g,h,w] = sum_{rbase valid, ic, xk, yk} Kc[g,rbase,pos,ic,o] * X[b,ic,src(g,rbase), h+xk-2, w+yk-2]
// Kc[...] = sum_f weight[o,ic,rbase,f] * basis[f,g,xk,yk]
// x: (8,16,12,128,128) f32; weight: (16,16,4,9) f32; basis: (9,12,5,5) f32; out: (8,16,12,128,128) f32
//
// R10: barrier-free wave-private pipeline. R6/R9 (86us) are lockstep-bound: block
// barriers align all 4 waves -> correlated ds_read bursts (LDS port queued) then
// correlated MFMA windows (port idle) -> ~58% port utilization vs the ~50us floor.
// Each wave now stages its OWN 12-halo-row window (rows w*8..w*8+11, 33% redundant
// fetch, HBM only 22%) into a PRIVATE double buffer; the only hazard is intra-wave
// DMA->ds_read, fenced by counted `s_waitcnt vmcnt(8)` (next slice's 8 DMA ops stay
// in flight). Zero __syncthreads in the main loop: 8 decoupled wave-streams/CU
// self-stagger the LDS port. Read layout stays the measured zero-conflict family.

#define NRS 12
#define CIN 16
#define COUT 16
#define HW 128
#define IMG (HW*HW)
#define ICSTRIDE (NRS*IMG)        // x stride between input channels (floats)

// fast-path geometry: per-wave slice window = [half(2)][rl(12)][cl(20)] 16B chunks
#define HALO_W 20
#define ROWB 320                  // bytes per halo row per half (20 px * 16 B)
#define WHALFB 3840               // 240 chunks * 16 B per ic-half per wave window
#define WCHUNK 480                // 12*20*2 real chunks per wave window
#define WBUF 8192                 // 512 chunk slots (8 issues x 64 lanes), 32 pad
#define PADW 132
#define PADROWB (PADW*32)         // 4224 B per padded row (132 px * 32 B)

typedef __bf16 bf16x8 __attribute__((ext_vector_type(8)));
typedef float  f32x4  __attribute__((ext_vector_type(4)));

__device__ __forceinline__ unsigned short f2bf(float f) {
    unsigned u = __builtin_bit_cast(unsigned, f);
    u += 0x7fffu + ((u >> 16) & 1u);          // round-nearest-even
    return (unsigned short)(u >> 16);
}

// A-panel: [g(12)][rbase(4)][pp(13)][o(16)][k(32)] bf16, k = possel*16 + ic, pos = 2*pp+possel
// pos==25 -> 0 (pad). 319488 elems = 639 KB.
__global__ void build_kc(const float* __restrict__ wgt, const float* __restrict__ basis,
                         unsigned short* __restrict__ kc) {
    int idx = blockIdx.x * 256 + threadIdx.x;
    const int total = 12 * 4 * 13 * 16 * 32;   // 319488
    if (idx >= total) return;
    int k  = idx & 31;
    int possel = k >> 4, ic = k & 15;
    int o  = (idx >> 5) & 15;
    int t2 = idx >> 9;
    int pp = t2 % 13;
    int gr = t2 / 13;
    int rbase = gr & 3, g = gr >> 2;
    int pos = 2 * pp + possel;
    float s = 0.f;
    if (pos < 25) {
        int xk = pos / 5, yk = pos - 5 * xk;
        #pragma unroll
        for (int f = 0; f < 9; ++f)
            s = fmaf(wgt[((o * CIN + ic) * 4 + rbase) * 9 + f],
                     basis[((f * NRS + g) * 5 + xk) * 5 + yk], s);
    }
    kc[idx] = f2bf(s);
}

// Pre-pass: x (b,ic,s,h,w) f32 -> xbf[b][s][hp 132][wp 132][ic 16] bf16, 2-px zero border.
__global__ void cvt_pad(const float* __restrict__ x, unsigned short* __restrict__ xbf) {
    int idx = blockIdx.x * 256 + threadIdx.x;
    const int total = 8 * 12 * PADW * PADW;    // 1,672,704
    if (idx >= total) return;
    int wp = idx % PADW;
    int t1 = idx / PADW;
    int hp = t1 % PADW;
    int bs = t1 / PADW;                        // b*12 + s
    int s  = bs % 12, bb = bs / 12;
    int h = hp - 2, w = wp - 2;
    bool ok = ((unsigned)h < 128u) && ((unsigned)w < 128u);
    const float* px = x + ((size_t)bb * 192 + s) * IMG + h * HW + w;   // +ic*12*IMG
    unsigned short v[16];
    #pragma unroll
    for (int ic = 0; ic < 16; ++ic) {
        float f = 0.f;
        if (ok) f = px[(size_t)ic * ICSTRIDE];
        v[ic] = f2bf(f);
    }
    uint4 lo, hi;
    lo.x = v[0] | (v[1] << 16);  lo.y = v[2] | (v[3] << 16);
    lo.z = v[4] | (v[5] << 16);  lo.w = v[6] | (v[7] << 16);
    hi.x = v[8] | (v[9] << 16);  hi.y = v[10] | (v[11] << 16);
    hi.z = v[12] | (v[13] << 16); hi.w = v[14] | (v[15] << 16);
    *(uint4*)(xbf + (size_t)idx * 16)     = lo;
    *(uint4*)(xbf + (size_t)idx * 16 + 8) = hi;
}

// Stage this wave's 12-row halo window (480 chunks) into its private LDS buffer.
// chunk c -> LDS byte c*16; c = hf*240 + rl*20 + cl; src = (wave rows already in sb).
__device__ __forceinline__ void stage_wave(const char* sb, char* lb, int lane) {
    #pragma unroll
    for (int j = 0; j < 8; ++j) {
        int c = j * 64 + lane; if (c > WCHUNK - 1) c = WCHUNK - 1;   // pad lanes: dup read
        int hf = c / 240, p = c - hf * 240;
        int rl = p / 20, cl = p - rl * 20;
        int soff = rl * PADROWB + cl * 32 + hf * 16;
        __builtin_amdgcn_global_load_lds(
            (const __attribute__((address_space(1))) void*)(sb + soff),
            (__attribute__((address_space(3))) void*)(lb + j * 1024), 16, 0, 0);
    }
}

__global__ __launch_bounds__(256, 2)
void conv_fast(const unsigned short* __restrict__ xbf, const unsigned short* __restrict__ kc,
               float* __restrict__ out) {
    const int b   = blockIdx.z;
    const int r0  = blockIdx.y;                    // 0..3 (r0-column of 3 g's)
    const int th0 = (blockIdx.x >> 3) * 32;        // 4 row-tiles of 32
    const int tw0 = (blockIdx.x & 7) * 16;         // 8 col-tiles of 16

    const int t    = threadIdx.x;
    const int lane = t & 63;
    const int wave = t >> 6;                       // 0..3, owns 8 output rows
    const int n    = lane & 15;        // MFMA N index
    const int q    = lane >> 4;
    const int possel = q >> 1;
    const int half_  = q & 1;

    __shared__ uint4 xs4[65536 / 16];              // 4 waves x 2 bufs x 8192 B
    char* xsc = (char*)xs4;
    char* mybase = xsc + wave * (2 * WBUF);

    // B-fragment byte offsets per K-step (zero-conflict family: 320B rows, 16B/lane)
    int boff[13];
    #pragma unroll
    for (int pp = 0; pp < 13; ++pp) {
        int pos = 2 * pp + possel; if (pos > 24) pos = 24;   // pad tap reads tap 24; A=0 there
        int dx = pos / 5, dy = pos - 5 * dx;
        boff[pp] = half_ * WHALFB + dx * ROWB + (n + dy) * 16;
    }
    const int aoff = n * 32 + q * 8;               // A-frag: o*32 + q*8 (ushort elems)

    f32x4 acc[3][8];
    #pragma unroll
    for (int s0 = 0; s0 < 3; ++s0)
        #pragma unroll
        for (int pg = 0; pg < 8; ++pg) acc[s0][pg] = (f32x4){0.f, 0.f, 0.f, 0.f};

    const char* xb0 = (const char*)xbf;
    // this wave's halo-window origin within a padded slice: rows th0+wave*8 .., col tw0
    const size_t waveoff = ((size_t)(th0 + wave * 8) * PADW + tw0) * 32;

    // prologue: stage slice (i=0, ss=0) into buf0 (8 DMA ops in flight)
    stage_wave(xb0 + ((size_t)(b * 12 + r0 * 3) * PADW * PADW) * 32 + waveoff, mybase, lane);

    int cur = 0;
    #pragma unroll 1
    for (int i = 0; i < 2; ++i) {                  // rolled: acc index never depends on i
        int rr = r0 + i; if (rr >= 4) rr -= 4;
        int rrn = rr + 1; if (rrn >= 4) rrn -= 4;
        #pragma unroll
        for (int ss = 0; ss < 3; ++ss) {           // unrolled: static acc[ss]/acc[ss-1]
            // ---- issue next slice's stage into my other buffer, then fence cur ----
            if (i == 0 || ss < 2) {
                int sin_next = (ss < 2) ? (rr * 3 + ss + 1) : (rrn * 3);
                stage_wave(xb0 + ((size_t)(b * 12 + sin_next) * PADW * PADW) * 32 + waveoff,
                           mybase + (cur ^ 1) * WBUF, lane);
                // wait until only the 8 just-issued ops remain -> buf[cur]'s DMA done
                asm volatile("s_waitcnt vmcnt(8)" ::: "memory");
            } else {
                asm volatile("s_waitcnt vmcnt(0)" ::: "memory");
            }

            // ---- GEMM over current slice: 13 K-steps x 8 pixel groups, 1-2 users ----
            // user j=0: g = r0*3+ss,   rbase = 2i   -> acc[ss]
            // user j=1: g = r0*3+ss-1, rbase = 2i+1 -> acc[ss-1]   (only ss>0)
            const unsigned short* kc0 = kc + (size_t)((r0 * 3 + ss) * 4 + 2 * i) * (13 * 512);
            const char* wb = mybase + cur * WBUF;
            if (ss > 0) {
                const unsigned short* kc1 = kc + (size_t)((r0 * 3 + ss - 1) * 4 + 2 * i + 1) * (13 * 512);
                #pragma unroll
                for (int pp = 0; pp < 13; ++pp) {
                    bf16x8 af0 = *(const bf16x8*)(kc0 + pp * 512 + aoff);
                    bf16x8 af1 = *(const bf16x8*)(kc1 + pp * 512 + aoff);
                    const char* wp = wb + boff[pp];
                    #pragma unroll
                    for (int pg = 0; pg < 8; ++pg) {
                        bf16x8 bfv = *(const bf16x8*)(wp + pg * ROWB);
                        acc[ss][pg]     = __builtin_amdgcn_mfma_f32_16x16x32_bf16(af0, bfv, acc[ss][pg], 0, 0, 0);
                        acc[ss - 1][pg] = __builtin_amdgcn_mfma_f32_16x16x32_bf16(af1, bfv, acc[ss - 1][pg], 0, 0, 0);
                    }
                }
            } else {
                #pragma unroll
                for (int pp = 0; pp < 13; ++pp) {
                    bf16x8 af0 = *(const bf16x8*)(kc0 + pp * 512 + aoff);
                    const char* wp = wb + boff[pp];
                    #pragma unroll
                    for (int pg = 0; pg < 8; ++pg) {
                        bf16x8 bfv = *(const bf16x8*)(wp + pg * ROWB);
                        acc[ss][pg] = __builtin_amdgcn_mfma_f32_16x16x32_bf16(af0, bfv, acc[ss][pg], 0, 0, 0);
                    }
                }
            }
            cur ^= 1;
        }
    }

    // ---- epilogue: D row = o = q*4+reg, col = pixel = n ----
    #pragma unroll
    for (int s0 = 0; s0 < 3; ++s0) {
        const size_t obase = ((size_t)b * COUT * NRS + (r0 * 3 + s0)) * IMG;
        #pragma unroll
        for (int pg = 0; pg < 8; ++pg) {
            int row = th0 + wave * 8 + pg;
            int col = tw0 + n;
            size_t pix = (size_t)row * HW + col;
            #pragma unroll
            for (int r = 0; r < 4; ++r) {
                int o = q * 4 + r;
                out[obase + (size_t)o * NRS * IMG + pix] = acc[s0][pg][r];
            }
        }
    }
}

// Fallback: direct-from-x version (R2/R6 structure), used only if workspace can't hold xbf.
__global__ __launch_bounds__(256, 2)
void conv_slow(const float* __restrict__ x, const unsigned short* __restrict__ kc,
               float* __restrict__ out) {
    const int b   = blockIdx.z;
    const int r0  = blockIdx.y;
    const int th0 = (blockIdx.x >> 3) * 32;
    const int tw0 = (blockIdx.x & 7) * 16;

    const int t    = threadIdx.x;
    const int lane = t & 63;
    const int wave = t >> 6;
    const int n    = lane & 15;
    const int q    = lane >> 4;
    const int possel = q >> 1;
    const int half_  = q & 1;

    __shared__ uint4 xs4[(2 * 11520) / 16];
    char* xsc = (char*)xs4;

    int boff[13];
    #pragma unroll
    for (int pp = 0; pp < 13; ++pp) {
        int pos = 2 * pp + possel; if (pos > 24) pos = 24;
        int dx = pos / 5, dy = pos - 5 * dx;
        boff[pp] = half_ * 11520 + dx * 320 + (n + dy) * 16;
    }
    const int aoff = n * 32 + q * 8;

    f32x4 acc[3][8];
    #pragma unroll
    for (int s0 = 0; s0 < 3; ++s0)
        #pragma unroll
        for (int pg = 0; pg < 8; ++pg) acc[s0][pg] = (f32x4){0.f, 0.f, 0.f, 0.f};

    #pragma unroll 1
    for (int i = 0; i < 2; ++i) {
        int rr = r0 + i; if (rr >= 4) rr -= 4;
        #pragma unroll
        for (int ss = 0; ss < 3; ++ss) {
            const int sin_ = rr * 3 + ss;
            const float* xb = x + ((size_t)b * CIN * NRS + sin_) * IMG;

            __syncthreads();
            for (int p = t; p < 720; p += 256) {
                int rl = p / HALO_W, cl = p - rl * HALO_W;
                int hh = th0 + rl - 2, ww = tw0 + cl - 2;
                bool ok = ((unsigned)hh < 128u) && ((unsigned)ww < 128u);
                const float* px = xb + hh * HW + ww;
                unsigned short v[16];
                #pragma unroll
                for (int ic = 0; ic < 16; ++ic) {
                    float f = 0.f;
                    if (ok) f = px[(size_t)ic * ICSTRIDE];
                    v[ic] = f2bf(f);
                }
                uint4 lo, hi;
                lo.x = v[0] | (v[1] << 16);  lo.y = v[2] | (v[3] << 16);
                lo.z = v[4] | (v[5] << 16);  lo.w = v[6] | (v[7] << 16);
                hi.x = v[8] | (v[9] << 16);  hi.y = v[10] | (v[11] << 16);
                hi.z = v[12] | (v[13] << 16); hi.w = v[14] | (v[15] << 16);
                *(uint4*)(xsc + p * 16)         = lo;
                *(uint4*)(xsc + 11520 + p * 16) = hi;
            }
            __syncthreads();

            const unsigned short* kc0 = kc + (size_t)((r0 * 3 + ss) * 4 + 2 * i) * (13 * 512);
            const unsigned short* kc1 = kc + (size_t)((r0 * 3 + ss - 1) * 4 + 2 * i + 1) * (13 * 512);
            const char* wb = xsc + wave * 8 * 320;
            #pragma unroll
            for (int pp = 0; pp < 13; ++pp) {
                bf16x8 af0 = *(const bf16x8*)(kc0 + pp * 512 + aoff);
                bf16x8 af1;
                if (ss > 0) af1 = *(const bf16x8*)(kc1 + pp * 512 + aoff);
                const char* wp = wb + boff[pp];
                #pragma unroll
                for (int pg = 0; pg < 8; ++pg) {
                    bf16x8 bfv = *(const bf16x8*)(wp + pg * 320);
                    acc[ss][pg] = __builtin_amdgcn_mfma_f32_16x16x32_bf16(af0, bfv, acc[ss][pg], 0, 0, 0);
                    if (ss > 0)
                        acc[ss - 1][pg] = __builtin_amdgcn_mfma_f32_16x16x32_bf16(af1, bfv, acc[ss - 1][pg], 0, 0, 0);
                }
            }
        }
    }

    #pragma unroll
    for (int s0 = 0; s0 < 3; ++s0) {
        const size_t obase = ((size_t)b * COUT * NRS + (r0 * 3 + s0)) * IMG;
        #pragma unroll
        for (int pg = 0; pg < 8; ++pg) {
            int row = th0 + wave * 8 + pg;
            int col = tw0 + n;
            size_t pix = (size_t)row * HW + col;
            #pragma unroll
            for (int r = 0; r < 4; ++r) {
                int o = q * 4 + r;
                out[obase + (size_t)o * NRS * IMG + pix] = acc[s0][pg][r];
            }
        }
    }
}

extern "C" void kernel_launch(void* const* d_in, const int* in_sizes, int n_in,
                              void* d_out, int out_size, void* d_ws, size_t ws_size,
                              hipStream_t stream) {
    const float* x      = (const float*)d_in[0];
    const float* weight = (const float*)d_in[1];
    const float* basis  = (const float*)d_in[2];
    float* out = (float*)d_out;
    unsigned short* kc = (unsigned short*)d_ws;            // 639 KB

    build_kc<<<dim3((12 * 4 * 13 * 16 * 32 + 255) / 256), dim3(256), 0, stream>>>(weight, basis, kc);

    const size_t xbf_off = 655360;                         // 640 KB, 16B-aligned
    const size_t xbf_bytes = (size_t)8 * 12 * PADW * PADW * 32;   // 53.5 MB
    if (ws_size >= xbf_off + xbf_bytes) {
        unsigned short* xbf = (unsigned short*)((char*)d_ws + xbf_off);
        cvt_pad<<<dim3((8 * 12 * PADW * PADW + 255) / 256), dim3(256), 0, stream>>>(x, xbf);
        conv_fast<<<dim3(32, 4, 8), dim3(256), 0, stream>>>(xbf, kc, out);
    } else {
        conv_slow<<<dim3(32, 4, 8), dim3(256), 0, stream>>>(x, kc, out);
    }
}